// Round 2
// baseline (205090.918 us; speedup 1.0000x reference)
//
#include <hip/hip_runtime.h>
#include <math.h>

#define BB    64
#define TT    2048
#define DIN   128
#define HH    512
#define NWG   256
#define NTHR  256
#define NCH   18        // chunks per super-step: 2 x-chunks + 8 h0 + 8 h1 (K=64 each)

struct Smem {
  float4 chunk[2][16*65];   // staged K=64 chunk, [k4][b] pad-65, double buffered (33,280 B)
  float  wih0[8*DIN];       // this WG's 8 gate rows of W_ih0 (4,096 B)
  float  whh0[8*HH];        // 16,384 B
  float  wih1[8*HH];
  float  whh1[8*HH];
  float  parts[4*16*64];    // K-split partial gate sums [rg][lr][b] (16,384 B)
  float  gates[16*64];      // reduced pre-activations [lr][b] (4,096 B)
  float  cst[2*2*64];       // c state [layer][ci][b], persistent across steps
  float  bias0[8];
  float  bias1[8];
  int    bar_dead;
};                          // total ~108,100 B

__device__ __forceinline__ float sigm(float v) { return 1.0f / (1.0f + expf(-v)); }

__device__ __forceinline__ void grid_barrier(unsigned* cnt, unsigned* gen, int* dead) {
  __threadfence();   // all threads: release-order own stores (cheap insurance)
  __syncthreads();
  if (threadIdx.x == 0) {
    if (*dead == 0) {
      __threadfence();  // release: wb this XCD's L2 (all WG stores drained by barrier's vmcnt0)
      unsigned g = __hip_atomic_load(gen, __ATOMIC_RELAXED, __HIP_MEMORY_SCOPE_AGENT);
      unsigned a = __hip_atomic_fetch_add(cnt, 1u, __ATOMIC_ACQ_REL, __HIP_MEMORY_SCOPE_AGENT);
      if (a == NWG - 1) {
        __hip_atomic_store(cnt, 0u, __ATOMIC_RELAXED, __HIP_MEMORY_SCOPE_AGENT);
        __hip_atomic_fetch_add(gen, 1u, __ATOMIC_RELEASE, __HIP_MEMORY_SCOPE_AGENT);
      } else {
        long spins = 0;
        while (__hip_atomic_load(gen, __ATOMIC_RELAXED, __HIP_MEMORY_SCOPE_AGENT) == g) {
          __builtin_amdgcn_s_sleep(2);
          if (++spins > (1L << 26)) { *dead = 1; break; }  // no-hang valve
        }
      }
      __threadfence();  // acquire: invalidate L1/L2 so we see remote h writes
    }
  }
  __syncthreads();
}

__global__ __launch_bounds__(NTHR, 1) void lstm2_fused(
    const float* __restrict__ x,
    const float* __restrict__ Wih0, const float* __restrict__ Whh0,
    const float* __restrict__ bih0, const float* __restrict__ bhh0,
    const float* __restrict__ Wih1, const float* __restrict__ Whh1,
    const float* __restrict__ bih1, const float* __restrict__ bhh1,
    const float* __restrict__ fcw,  const float* __restrict__ fcb,
    float* __restrict__ out, float* __restrict__ ws)
{
  extern __shared__ char smem_raw[];
  Smem& s = *reinterpret_cast<Smem*>(smem_raw);
  const int tid = threadIdx.x;
  const int wg  = blockIdx.x;

  float* h0s = ws;                 // 2 buffers x [64][512]
  float* h1s = ws + 2*BB*HH;       // 2 buffers x [64][512]
  unsigned* bar = reinterpret_cast<unsigned*>(ws + 4*BB*HH);

  const int col0 = 2*wg;           // this WG owns h-columns col0, col0+1 of both layers

  // ---- load weight slices into LDS (once; reused for all 2048 steps) ----
  for (int i = tid; i < 8*DIN; i += NTHR) {
    int lr = i >> 7, k = i & (DIN-1);
    int row = (lr >> 1)*HH + col0 + (lr & 1);   // lr = gate*2 + ci
    s.wih0[i] = Wih0[row*DIN + k];
  }
  for (int i = tid; i < 8*HH; i += NTHR) {
    int lr = i >> 9, k = i & (HH-1);
    int row = (lr >> 1)*HH + col0 + (lr & 1);
    s.whh0[i] = Whh0[row*HH + k];
    s.wih1[i] = Wih1[row*HH + k];
    s.whh1[i] = Whh1[row*HH + k];
  }
  if (tid < 8) {
    int row = (tid >> 1)*HH + col0 + (tid & 1);
    s.bias0[tid] = bih0[row] + bhh0[row];
    s.bias1[tid] = bih1[row] + bhh1[row];
  }
  for (int i = tid; i < 2*2*64; i += NTHR) s.cst[i] = 0.0f;
  if (tid == 0) s.bar_dead = 0;
  __syncthreads();

  const int b  = tid & 63;   // batch lane
  const int rg = tid >> 6;   // K-split group (one per wave)

  float4 sreg[4];
  const float4* x4 = reinterpret_cast<const float4*>(x);

  // K=64 chunk: 16 f4-rows x 64 batches = 1024 float4; 4 per thread, coalesced:
  // id = tid + 256*j; b-row = id>>4, f4-col kk = id&15 (16 consecutive lanes read 256B of one row)
  auto load_x = [&](int t, int c) {
#pragma unroll
    for (int j = 0; j < 4; ++j) {
      int id = tid + NTHR*j;
      int bb = id >> 4, kk = id & 15;
      sreg[j] = x4[bb*(TT*DIN/4) + t*(DIN/4) + c*16 + kk];
    }
  };
  auto load_h = [&](const float* hb, int c) {
    const float4* h4 = reinterpret_cast<const float4*>(hb);
#pragma unroll
    for (int j = 0; j < 4; ++j) {
      int id = tid + NTHR*j;
      int bb = id >> 4, kk = id & 15;
      sreg[j] = h4[bb*(HH/4) + c*16 + kk];
    }
  };
  auto store_chunk = [&](int bi) {
#pragma unroll
    for (int j = 0; j < 4; ++j) {
      int id = tid + NTHR*j;
      int bb = id >> 4, kk = id & 15;
      s.chunk[bi][kk*65 + bb] = sreg[j];
    }
  };

  float aL0[8], aL1[8];

  load_x(0, 0);
  store_chunk(0);   // chunk parity is static: ch uses buf ch&1 (NCH=18 even)

  // Super-step st: layer0 computes t=st (st<TT); layer1 computes t=st-1 (st>=1).
  // h buffers: read buf[st&1], write buf[(st+1)&1]. One grid barrier per super-step.
  for (int st = 0; st <= TT; ++st) {
#pragma unroll
    for (int i = 0; i < 8; ++i) { aL0[i] = 0.f; aL1[i] = 0.f; }
    const float* h0r = h0s + (st & 1)*(BB*HH);
    const float* h1r = h1s + (st & 1)*(BB*HH);

    // chunks: 0,1 = x(st) halves; 2..9 = h0 (K=512); 10..17 = h1 (K=512)
    for (int ch = 0; ch < NCH; ++ch) {
      __syncthreads();
      bool doload;
      if (ch == 17)      { doload = (st <= TT-2); if (doload) load_x(st+1, 0); }  // cross-barrier x prefetch
      else if (ch == 0)  { doload = (st < TT);    if (doload) load_x(st, 1); }
      else               { doload = true;
                           if (ch < 9) load_h(h0r, ch-1);   // prefetch for ch+1 (h0 chunk (ch+1)-2)
                           else        load_h(h1r, ch-9); } // h1 chunk (ch+1)-10

      const int bi = ch & 1;
      if (ch < 2) {
        const int kbase = ch*64;
#pragma unroll
        for (int kkl = 0; kkl < 4; ++kkl) {
          float4 hv = s.chunk[bi][(rg*4 + kkl)*65 + b];
          const int ko = kbase + (rg*4 + kkl)*4;
#pragma unroll
          for (int lr = 0; lr < 8; ++lr) {
            float4 w = *reinterpret_cast<const float4*>(&s.wih0[lr*DIN + ko]);
            aL0[lr] += hv.x*w.x + hv.y*w.y + hv.z*w.z + hv.w*w.w;
          }
        }
      } else if (ch < 10) {
        const int kbase = (ch - 2)*64;
#pragma unroll
        for (int kkl = 0; kkl < 4; ++kkl) {
          float4 hv = s.chunk[bi][(rg*4 + kkl)*65 + b];
          const int ko = kbase + (rg*4 + kkl)*4;
#pragma unroll
          for (int lr = 0; lr < 8; ++lr) {
            float4 w0 = *reinterpret_cast<const float4*>(&s.whh0[lr*HH + ko]);
            aL0[lr] += hv.x*w0.x + hv.y*w0.y + hv.z*w0.z + hv.w*w0.w;
          }
#pragma unroll
          for (int lr = 0; lr < 8; ++lr) {
            float4 w1 = *reinterpret_cast<const float4*>(&s.wih1[lr*HH + ko]);
            aL1[lr] += hv.x*w1.x + hv.y*w1.y + hv.z*w1.z + hv.w*w1.w;
          }
        }
      } else {
        const int kbase = (ch - 10)*64;
#pragma unroll
        for (int kkl = 0; kkl < 4; ++kkl) {
          float4 hv = s.chunk[bi][(rg*4 + kkl)*65 + b];
          const int ko = kbase + (rg*4 + kkl)*4;
#pragma unroll
          for (int lr = 0; lr < 8; ++lr) {
            float4 w1 = *reinterpret_cast<const float4*>(&s.whh1[lr*HH + ko]);
            aL1[lr] += hv.x*w1.x + hv.y*w1.y + hv.z*w1.z + hv.w*w1.w;
          }
        }
      }
      if (doload) store_chunk((ch + 1) & 1);
    }

    // K-split partial reduction
#pragma unroll
    for (int lr = 0; lr < 8; ++lr) {
      s.parts[rg*1024 + lr*64 + b]       = aL0[lr];
      s.parts[rg*1024 + (8 + lr)*64 + b] = aL1[lr];
    }
    __syncthreads();
#pragma unroll
    for (int j = 0; j < 4; ++j) {
      int p  = tid + NTHR*j;
      int lr = p >> 6, pb = p & 63;
      float v = s.parts[lr*64 + pb] + s.parts[1024 + lr*64 + pb]
              + s.parts[2048 + lr*64 + pb] + s.parts[3072 + lr*64 + pb];
      v += (lr < 8) ? s.bias0[lr] : s.bias1[lr - 8];
      s.gates[lr*64 + pb] = v;
    }
    __syncthreads();

    // gate nonlinearities + state update (wave0/1: layer0 ci0/1; wave2/3: layer1)
    {
      const int layer = tid >> 7;
      const int ci    = (tid >> 6) & 1;
      const int ub    = tid & 63;
      const bool act  = (layer == 0) ? (st < TT) : (st >= 1);
      if (act) {
        const int gb = layer*8;
        float gi = sigm (s.gates[(gb + 0 + ci)*64 + ub]);
        float gf = sigm (s.gates[(gb + 2 + ci)*64 + ub]);
        float gg = tanhf(s.gates[(gb + 4 + ci)*64 + ub]);
        float go = sigm (s.gates[(gb + 6 + ci)*64 + ub]);
        float cprev = s.cst[(layer*2 + ci)*64 + ub];
        float cnew  = gf*cprev + gi*gg;
        s.cst[(layer*2 + ci)*64 + ub] = cnew;
        float hnew = go * tanhf(cnew);
        float* dst = (layer == 0 ? h0s : h1s) + ((st + 1) & 1)*(BB*HH);
        // agent-scope store: write-through to coherence point (visibility insurance)
        __hip_atomic_store(&dst[ub*HH + col0 + ci], hnew,
                           __ATOMIC_RELAXED, __HIP_MEMORY_SCOPE_AGENT);
      }
    }
    grid_barrier(bar, bar + 1, &s.bar_dead);
  }

  // ---- FC on last timestep's h1 (buffer 1 after st=TT) ----
  {
    const float* h1f = h1s + (BB*HH);
    int gt   = wg*NTHR + tid;           // 65536 threads, 8 per output
    int oidx = gt >> 3, kp = gt & 7;
    int ob   = oidx >> 7, on = oidx & 127;
    const float* hrow = h1f + ob*HH + kp*64;
    const float* wrow = fcw + on*HH + kp*64;
    float p = 0.f;
#pragma unroll
    for (int k = 0; k < 64; ++k) p += hrow[k]*wrow[k];
    p += __shfl_xor(p, 1);
    p += __shfl_xor(p, 2);
    p += __shfl_xor(p, 4);
    if (kp == 0) out[oidx] = p + fcb[on];
  }
}

__global__ void sentinel_fail(float* out) { out[threadIdx.x] = 1.0e6f; }

extern "C" void kernel_launch(void* const* d_in, const int* in_sizes, int n_in,
                              void* d_out, int out_size, void* d_ws, size_t ws_size,
                              hipStream_t stream) {
  const float* x    = (const float*)d_in[0];
  const float* Wih0 = (const float*)d_in[1];
  const float* Whh0 = (const float*)d_in[2];
  const float* bih0 = (const float*)d_in[3];
  const float* bhh0 = (const float*)d_in[4];
  const float* Wih1 = (const float*)d_in[5];
  const float* Whh1 = (const float*)d_in[6];
  const float* bih1 = (const float*)d_in[7];
  const float* bhh1 = (const float*)d_in[8];
  const float* fcw  = (const float*)d_in[9];
  const float* fcb  = (const float*)d_in[10];
  float* out = (float*)d_out;
  float* ws  = (float*)d_ws;
  (void)in_sizes; (void)n_in; (void)out_size; (void)ws_size;

  const int smem_bytes = (int)sizeof(Smem);
  hipFuncSetAttribute(reinterpret_cast<const void*>(&lstm2_fused),
                      hipFuncAttributeMaxDynamicSharedMemorySize, smem_bytes);

  // zero h-state buffers (both parities) + barrier counters every call
  hipMemsetAsync(d_ws, 0, (size_t)(4*BB*HH)*sizeof(float) + 256, stream);

  (void)hipGetLastError();  // clear any stale error
  // NORMAL launch (not cooperative): LDS 108KB forces 1 WG/CU, grid=256=#CUs
  // => all WGs co-resident structurally; hand-rolled barrier handles sync.
  lstm2_fused<<<dim3(NWG), dim3(NTHR), smem_bytes, stream>>>(
      x, Wih0, Whh0, bih0, bhh0, Wih1, Whh1, bih1, bhh1, fcw, fcb, out, ws);
  hipError_t e = hipGetLastError();
  if (e != hipSuccess) {
    // diagnostic sentinel: absmax ~1e6 next round means "launch failed", not logic
    sentinel_fail<<<1, 256, 0, stream>>>(out);
  }
}

// Round 4
// 84264.691 us; speedup vs baseline: 2.4339x; 2.4339x over previous
//
#include <hip/hip_runtime.h>
#include <hip/hip_fp16.h>
#include <math.h>

#define BB    64
#define TT    2048
#define DIN   128
#define HH    512
#define NWG   256
#define NTHR  256
#define NCH   18        // chunks per super-step: 2 x-chunks + 8 h0 + 8 h1 (K=64 each)

struct Smem {
  float4 chunk[2][16*65];   // staged K=64 chunk, [k4][b] pad-65, double buffered (33,280 B)
  float  wih0[8*DIN];       // this WG's 8 gate rows of W_ih0 (4,096 B)
  float  whh0[8*HH];        // 16,384 B
  float  wih1[8*HH];
  float  whh1[8*HH];
  float  parts[4*16*64];    // K-split partial gate sums [rg][lr][b] (16,384 B)
  float  gates[16*64];      // reduced pre-activations [lr][b] (4,096 B)
  float  cst[2*2*64];       // c state [layer][ci][b], persistent across steps
  float  bias0[8];
  float  bias1[8];
  int    bar_dead;
};                          // total ~108,100 B

__device__ __forceinline__ float sigm(float v) { return 1.0f / (1.0f + expf(-v)); }

// Two-level grid barrier. ALL cross-WG data (h-state, counters) moves via
// agent-scope atomics (MALL coherence point) -> no fences in the loop.
// Init coherence is established by prep_flush + prep_zero dispatches.
// bar layout (u32 words): gen = bar[0]; root = bar[32]; grp[i] = bar[64+i*32]
__device__ __forceinline__ void grid_barrier(unsigned* bar, int grp, int* dead) {
  __syncthreads();   // compiler emits vmcnt(0) drain per wave before s_barrier
  if (threadIdx.x == 0 && *dead == 0) {
    asm volatile("s_waitcnt vmcnt(0)" ::: "memory");
    unsigned* gen  = bar;
    unsigned* root = bar + 32;
    unsigned* gcnt = bar + 64 + grp*32;
    unsigned g0 = __hip_atomic_load(gen, __ATOMIC_RELAXED, __HIP_MEMORY_SCOPE_AGENT);
    unsigned a  = __hip_atomic_fetch_add(gcnt, 1u, __ATOMIC_RELAXED, __HIP_MEMORY_SCOPE_AGENT);
    if (a == 31) {
      unsigned r = __hip_atomic_fetch_add(root, 1u, __ATOMIC_RELAXED, __HIP_MEMORY_SCOPE_AGENT);
      if (r == 7) {
        // last arriver of last group: reset counters, publish new generation
#pragma unroll
        for (int i = 0; i < 8; ++i)
          __hip_atomic_store(bar + 64 + i*32, 0u, __ATOMIC_RELAXED, __HIP_MEMORY_SCOPE_AGENT);
        __hip_atomic_store(root, 0u, __ATOMIC_RELAXED, __HIP_MEMORY_SCOPE_AGENT);
        asm volatile("s_waitcnt vmcnt(0)" ::: "memory");  // resets reach MALL before gen flips
        __hip_atomic_store(gen, g0 + 1u, __ATOMIC_RELAXED, __HIP_MEMORY_SCOPE_AGENT);
      }
    }
    long spins = 0;
    while (__hip_atomic_load(gen, __ATOMIC_RELAXED, __HIP_MEMORY_SCOPE_AGENT) == g0) {
      __builtin_amdgcn_s_sleep(4);
      if (++spins > (1L << 22)) { *dead = 1; break; }  // no-hang valve
    }
    asm volatile("" ::: "memory");
  }
  __syncthreads();
}

// prep_flush: 108KB LDS forces 1 WG/CU; grid=256 = all CUs -> every XCD L2
// gets a wbl2+inv, flushing harness-poison / stale dirty lines of d_ws to
// MALL BEFORE prep_zero writes zeros there. Dispatch order = the sync.
__global__ __launch_bounds__(64, 1) void prep_flush() {
  extern __shared__ char dummy[];
  if (threadIdx.x == 0) {
    __threadfence();            // buffer_wbl2 sc1 + vmcnt + buffer_inv sc1
    dummy[0] = 0;               // keep LDS allocation honest
  }
  __syncthreads();
}

// prep_zero: zero h-state (fp16, 256KB) + barrier words via agent-scope
// atomic stores -> values land at the MALL coherence point directly.
__global__ void prep_zero(unsigned* w) {
  const int total = (4*BB*HH*2 + 2048) / 4;   // h region (fp16) + barrier words
  for (int i = blockIdx.x*blockDim.x + threadIdx.x; i < total; i += gridDim.x*blockDim.x)
    __hip_atomic_store(w + i, 0u, __ATOMIC_RELAXED, __HIP_MEMORY_SCOPE_AGENT);
}

__global__ __launch_bounds__(NTHR, 1) void lstm2_fused(
    const float* __restrict__ x,
    const float* __restrict__ Wih0, const float* __restrict__ Whh0,
    const float* __restrict__ bih0, const float* __restrict__ bhh0,
    const float* __restrict__ Wih1, const float* __restrict__ Whh1,
    const float* __restrict__ bih1, const float* __restrict__ bhh1,
    const float* __restrict__ fcw,  const float* __restrict__ fcb,
    float* __restrict__ out, float* __restrict__ ws)
{
  extern __shared__ char smem_raw[];
  Smem& s = *reinterpret_cast<Smem*>(smem_raw);
  const int tid = threadIdx.x;
  const int wg  = blockIdx.x;

  __half* h0s = reinterpret_cast<__half*>(ws);   // 2 buffers x [64][512] fp16
  __half* h1s = h0s + 2*BB*HH;                   // 2 buffers x [64][512] fp16
  unsigned* bar = reinterpret_cast<unsigned*>(h0s + 4*BB*HH);

  const int col0 = 2*wg;           // this WG owns h-columns col0, col0+1 of both layers
  const int grp  = wg >> 5;        // barrier group (8 groups x 32 WGs)

  // ---- load weight slices into LDS (once; reused for all 2048 steps) ----
  for (int i = tid; i < 8*DIN; i += NTHR) {
    int lr = i >> 7, k = i & (DIN-1);
    int row = (lr >> 1)*HH + col0 + (lr & 1);   // lr = gate*2 + ci
    s.wih0[i] = Wih0[row*DIN + k];
  }
  for (int i = tid; i < 8*HH; i += NTHR) {
    int lr = i >> 9, k = i & (HH-1);
    int row = (lr >> 1)*HH + col0 + (lr & 1);
    s.whh0[i] = Whh0[row*HH + k];
    s.wih1[i] = Wih1[row*HH + k];
    s.whh1[i] = Whh1[row*HH + k];
  }
  if (tid < 8) {
    int row = (tid >> 1)*HH + col0 + (tid & 1);
    s.bias0[tid] = bih0[row] + bhh0[row];
    s.bias1[tid] = bih1[row] + bhh1[row];
  }
  for (int i = tid; i < 2*2*64; i += NTHR) s.cst[i] = 0.0f;
  if (tid == 0) s.bar_dead = 0;
  __syncthreads();

  const int b  = tid & 63;   // batch lane
  const int rg = tid >> 6;   // K-split group (one per wave)

  float4 sreg[4];
  const float4* x4 = reinterpret_cast<const float4*>(x);

  // K=64 chunk: 64 k-values x 64 batches; 4 loads per thread, coalesced
  auto load_x = [&](int t, int c) {
#pragma unroll
    for (int j = 0; j < 4; ++j) {
      int id = tid + NTHR*j;
      int bb = id >> 4, kk = id & 15;
      sreg[j] = x4[bb*(TT*DIN/4) + t*(DIN/4) + c*16 + kk];
    }
  };
  // h loads: agent-scope 8B atomic loads (bypass L1/L2, MALL-coherent),
  // fp16 -> fp32 convert in-register.
  auto load_h = [&](const __half* hb, int c) {
    const unsigned long long* h8 = reinterpret_cast<const unsigned long long*>(hb);
#pragma unroll
    for (int j = 0; j < 4; ++j) {
      int id = tid + NTHR*j;
      int bb = id >> 4, kk = id & 15;
      unsigned long long v = __hip_atomic_load(&h8[bb*(HH/4) + c*16 + kk],
                              __ATOMIC_RELAXED, __HIP_MEMORY_SCOPE_AGENT);
      __half2 h01 = __builtin_bit_cast(__half2, (unsigned)(v & 0xffffffffull));
      __half2 h23 = __builtin_bit_cast(__half2, (unsigned)(v >> 32));
      float2 f01 = __half22float2(h01);
      float2 f23 = __half22float2(h23);
      sreg[j] = make_float4(f01.x, f01.y, f23.x, f23.y);
    }
  };
  auto store_chunk = [&](int bi) {
#pragma unroll
    for (int j = 0; j < 4; ++j) {
      int id = tid + NTHR*j;
      int bb = id >> 4, kk = id & 15;
      s.chunk[bi][kk*65 + bb] = sreg[j];
    }
  };

  float aL0[8], aL1[8];

  load_x(0, 0);
  store_chunk(0);   // chunk parity is static: ch uses buf ch&1 (NCH=18 even)

  // Super-step st: layer0 computes t=st (st<TT); layer1 computes t=st-1 (st>=1).
  // h buffers: read buf[st&1], write buf[(st+1)&1]. One grid barrier per super-step.
  for (int st = 0; st <= TT; ++st) {
#pragma unroll
    for (int i = 0; i < 8; ++i) { aL0[i] = 0.f; aL1[i] = 0.f; }
    const __half* h0r = h0s + (st & 1)*(BB*HH);
    const __half* h1r = h1s + (st & 1)*(BB*HH);

    // chunks: 0,1 = x(st) halves; 2..9 = h0 (K=512); 10..17 = h1 (K=512)
    for (int ch = 0; ch < NCH; ++ch) {
      __syncthreads();
      bool doload;
      if (ch == 17)      { doload = (st <= TT-2); if (doload) load_x(st+1, 0); }  // cross-barrier x prefetch
      else if (ch == 0)  { doload = (st < TT);    if (doload) load_x(st, 1); }
      else               { doload = true;
                           if (ch < 9) load_h(h0r, ch-1);   // prefetch for ch+1
                           else        load_h(h1r, ch-9); }

      const int bi = ch & 1;
      if (ch < 2) {
        const int kbase = ch*64;
#pragma unroll
        for (int kkl = 0; kkl < 4; ++kkl) {
          float4 hv = s.chunk[bi][(rg*4 + kkl)*65 + b];
          const int ko = kbase + (rg*4 + kkl)*4;
#pragma unroll
          for (int lr = 0; lr < 8; ++lr) {
            float4 w = *reinterpret_cast<const float4*>(&s.wih0[lr*DIN + ko]);
            aL0[lr] += hv.x*w.x + hv.y*w.y + hv.z*w.z + hv.w*w.w;
          }
        }
      } else if (ch < 10) {
        const int kbase = (ch - 2)*64;
#pragma unroll
        for (int kkl = 0; kkl < 4; ++kkl) {
          float4 hv = s.chunk[bi][(rg*4 + kkl)*65 + b];
          const int ko = kbase + (rg*4 + kkl)*4;
#pragma unroll
          for (int lr = 0; lr < 8; ++lr) {
            float4 w0 = *reinterpret_cast<const float4*>(&s.whh0[lr*HH + ko]);
            aL0[lr] += hv.x*w0.x + hv.y*w0.y + hv.z*w0.z + hv.w*w0.w;
          }
#pragma unroll
          for (int lr = 0; lr < 8; ++lr) {
            float4 w1 = *reinterpret_cast<const float4*>(&s.wih1[lr*HH + ko]);
            aL1[lr] += hv.x*w1.x + hv.y*w1.y + hv.z*w1.z + hv.w*w1.w;
          }
        }
      } else {
        const int kbase = (ch - 10)*64;
#pragma unroll
        for (int kkl = 0; kkl < 4; ++kkl) {
          float4 hv = s.chunk[bi][(rg*4 + kkl)*65 + b];
          const int ko = kbase + (rg*4 + kkl)*4;
#pragma unroll
          for (int lr = 0; lr < 8; ++lr) {
            float4 w1 = *reinterpret_cast<const float4*>(&s.whh1[lr*HH + ko]);
            aL1[lr] += hv.x*w1.x + hv.y*w1.y + hv.z*w1.z + hv.w*w1.w;
          }
        }
      }
      if (doload) store_chunk((ch + 1) & 1);
    }

    // K-split partial reduction
#pragma unroll
    for (int lr = 0; lr < 8; ++lr) {
      s.parts[rg*1024 + lr*64 + b]       = aL0[lr];
      s.parts[rg*1024 + (8 + lr)*64 + b] = aL1[lr];
    }
    __syncthreads();
#pragma unroll
    for (int j = 0; j < 4; ++j) {
      int p  = tid + NTHR*j;
      int lr = p >> 6, pb = p & 63;
      float v = s.parts[lr*64 + pb] + s.parts[1024 + lr*64 + pb]
              + s.parts[2048 + lr*64 + pb] + s.parts[3072 + lr*64 + pb];
      v += (lr < 8) ? s.bias0[lr] : s.bias1[lr - 8];
      s.gates[lr*64 + pb] = v;
    }
    __syncthreads();

    // gate nonlinearities + state update. Wave 0: layer0 (both ci),
    // wave 1: layer1 (both ci) -> each thread packs its 2 cols into one
    // u32 fp16 pair for a single agent-scope store.
    {
      const int sel = tid >> 6;
      const int ub  = tid & 63;
      if (sel < 2) {
        const int layer = sel;
        const bool act  = (layer == 0) ? (st < TT) : (st >= 1);
        if (act) {
          const int gb = layer*8;
          float hv[2];
#pragma unroll
          for (int ci = 0; ci < 2; ++ci) {
            float gi = sigm (s.gates[(gb + 0 + ci)*64 + ub]);
            float gf = sigm (s.gates[(gb + 2 + ci)*64 + ub]);
            float gg = tanhf(s.gates[(gb + 4 + ci)*64 + ub]);
            float go = sigm (s.gates[(gb + 6 + ci)*64 + ub]);
            float cprev = s.cst[(layer*2 + ci)*64 + ub];
            float cnew  = gf*cprev + gi*gg;
            s.cst[(layer*2 + ci)*64 + ub] = cnew;
            hv[ci] = go * tanhf(cnew);
          }
          __half2 hp = __floats2half2_rn(hv[0], hv[1]);
          unsigned pu = __builtin_bit_cast(unsigned, hp);
          unsigned* dst = reinterpret_cast<unsigned*>(
              (layer == 0 ? h0s : h1s) + ((st + 1) & 1)*(BB*HH));
          __hip_atomic_store(dst + ub*(HH/2) + wg, pu,
                             __ATOMIC_RELAXED, __HIP_MEMORY_SCOPE_AGENT);
        }
      }
    }
    grid_barrier(bar, grp, &s.bar_dead);
  }

  // ---- FC on last timestep's h1 (buffer 1 after st=TT) ----
  // Normal loads safe: no L2 line of the h region exists (all traffic was
  // L2-bypassing), so misses fill from MALL with current values.
  {
    const __half* h1f = h1s + (BB*HH);
    int gt   = wg*NTHR + tid;           // 65536 threads, 8 per output
    int oidx = gt >> 3, kp = gt & 7;
    int ob   = oidx >> 7, on = oidx & 127;
    const __half* hrow = h1f + ob*HH + kp*64;
    const float*  wrow = fcw + on*HH + kp*64;
    float p = 0.f;
#pragma unroll
    for (int k = 0; k < 64; ++k) p += __half2float(hrow[k]) * wrow[k];
    p += __shfl_xor(p, 1);
    p += __shfl_xor(p, 2);
    p += __shfl_xor(p, 4);
    if (kp == 0) out[oidx] = p + fcb[on];
  }
}

__global__ void sentinel_fail(float* out) { out[threadIdx.x] = 1.0e6f; }

extern "C" void kernel_launch(void* const* d_in, const int* in_sizes, int n_in,
                              void* d_out, int out_size, void* d_ws, size_t ws_size,
                              hipStream_t stream) {
  const float* x    = (const float*)d_in[0];
  const float* Wih0 = (const float*)d_in[1];
  const float* Whh0 = (const float*)d_in[2];
  const float* bih0 = (const float*)d_in[3];
  const float* bhh0 = (const float*)d_in[4];
  const float* Wih1 = (const float*)d_in[5];
  const float* Whh1 = (const float*)d_in[6];
  const float* bih1 = (const float*)d_in[7];
  const float* bhh1 = (const float*)d_in[8];
  const float* fcw  = (const float*)d_in[9];
  const float* fcb  = (const float*)d_in[10];
  float* out = (float*)d_out;
  float* ws  = (float*)d_ws;
  (void)in_sizes; (void)n_in; (void)out_size; (void)ws_size;

  const int smem_bytes = (int)sizeof(Smem);
  hipFuncSetAttribute(reinterpret_cast<const void*>(&lstm2_fused),
                      hipFuncAttributeMaxDynamicSharedMemorySize, smem_bytes);
  hipFuncSetAttribute(reinterpret_cast<const void*>(&prep_flush),
                      hipFuncAttributeMaxDynamicSharedMemorySize, smem_bytes);

  (void)hipGetLastError();  // clear stale error
  // 1) flush every XCD's L2 (dirty poison/blit lines of d_ws -> MALL, then inv)
  prep_flush<<<dim3(NWG), dim3(64), smem_bytes, stream>>>();
  // 2) zero h-state + barrier words directly at MALL via agent-scope stores
  prep_zero<<<dim3(NWG), dim3(NTHR), 0, stream>>>((unsigned*)d_ws);
  // 3) main persistent kernel (1 WG/CU by LDS capacity; grid=256=#CUs)
  lstm2_fused<<<dim3(NWG), dim3(NTHR), smem_bytes, stream>>>(
      x, Wih0, Whh0, bih0, bhh0, Wih1, Whh1, bih1, bhh1, fcw, fcb, out, ws);
  hipError_t e = hipGetLastError();
  if (e != hipSuccess) {
    // diagnostic sentinel: absmax ~1e6 next round means "launch failed", not logic
    sentinel_fail<<<1, 256, 0, stream>>>(out);
  }
}

// Round 6
// 11834.005 us; speedup vs baseline: 17.3306x; 7.1206x over previous
//
#include <hip/hip_runtime.h>
#include <hip/hip_fp16.h>
#include <math.h>

#define BB    64
#define TT    2048
#define DIN   128
#define HH    512
#define NWG   256
#define NTHR  256

typedef __attribute__((ext_vector_type(4))) unsigned int u32x4;
typedef __attribute__((ext_vector_type(8))) _Float16    f16x8;
typedef __attribute__((ext_vector_type(4))) float       f32x4;

struct Smem {
  char  ring[4][64*128];     // 32 KB staging ring: 4 chunks x (64 b-rows x 64 halves)
  float gates[16*64];        // 4 KB pre-activations [row r=layer*8+gate*2+ci][b]
  float cst[2*2*64];         // c state [layer][ci][b]
  float bias0[8], bias1[8];
  int   bar_dead;
};                           // ~37.3 KB used; launched with 108 KB to force 1 WG/CU

__device__ __forceinline__ float sigm(float v) { return 1.0f / (1.0f + expf(-v)); }

// Monotonic two-level grid barrier; all cross-WG data via agent-scope (MALL) ops.
__device__ __forceinline__ void grid_barrier(unsigned* bar, int grp, unsigned target, int* dead) {
  __syncthreads();
  if (threadIdx.x == 0 && *dead == 0) {
    asm volatile("s_waitcnt vmcnt(0)" ::: "memory");
    unsigned* gen  = bar;
    unsigned* root = bar + 32;
    unsigned* gcnt = bar + 64 + grp*32;
    unsigned a = __hip_atomic_fetch_add(gcnt, 1u, __ATOMIC_RELAXED, __HIP_MEMORY_SCOPE_AGENT);
    if (a == target*32u - 1u) {
      unsigned r = __hip_atomic_fetch_add(root, 1u, __ATOMIC_RELAXED, __HIP_MEMORY_SCOPE_AGENT);
      if (r == target*8u - 1u)
        __hip_atomic_store(gen, target, __ATOMIC_RELAXED, __HIP_MEMORY_SCOPE_AGENT);
    }
    long spins = 0;
    while (__hip_atomic_load(gen, __ATOMIC_RELAXED, __HIP_MEMORY_SCOPE_AGENT) < target) {
      __builtin_amdgcn_s_sleep(1);
      if (++spins > (1L << 22)) { *dead = 1; break; }
    }
    asm volatile("" ::: "memory");
  }
  __syncthreads();
}

// Flush every XCD's L2 (poison / stale dirty d_ws lines -> MALL, then inv).
__global__ __launch_bounds__(64, 1) void prep_flush() {
  extern __shared__ char dummy[];
  if (threadIdx.x == 0) { __threadfence(); dummy[0] = 0; }
  __syncthreads();
}

// Zero h-state + barrier words directly at MALL.
__global__ void prep_zero(unsigned* w) {
  const int total = (4*BB*HH*2 + 2048) / 4;
  for (int i = blockIdx.x*blockDim.x + threadIdx.x; i < total; i += gridDim.x*blockDim.x)
    __hip_atomic_store(w + i, 0u, __ATOMIC_RELAXED, __HIP_MEMORY_SCOPE_AGENT);
}

// x -> fp16 into ws (MALL-direct stores; readers bypass L2).
__global__ void xcvt(const float* __restrict__ x, unsigned long long* __restrict__ xh) {
  const int N4 = BB*TT*DIN/4;
  const float4* x4 = reinterpret_cast<const float4*>(x);
  for (int i = blockIdx.x*blockDim.x + threadIdx.x; i < N4; i += gridDim.x*blockDim.x) {
    float4 v = x4[i];
    __half2 a = __floats2half2_rn(v.x, v.y);
    __half2 b = __floats2half2_rn(v.z, v.w);
    unsigned long long u = ((unsigned long long)__builtin_bit_cast(unsigned, b) << 32)
                         |  (unsigned long long)__builtin_bit_cast(unsigned, a);
    __hip_atomic_store(&xh[i], u, __ATOMIC_RELAXED, __HIP_MEMORY_SCOPE_AGENT);
  }
}

#define WAITV(N) do { asm volatile("s_waitcnt vmcnt(" #N ")" ::: "memory"); \
                      __builtin_amdgcn_sched_barrier(0); } while (0)

#define ISSUE(c) do { \
  const __half* _b; int _str; \
  if ((c) < 2)       { _b = xh + tcur*DIN + (c)*64;   _str = TT*DIN; } \
  else if ((c) < 10) { _b = h0r + ((c)-2)*64;         _str = HH;     } \
  else               { _b = h1r + ((c)-10)*64;        _str = HH;     } \
  const __half* _p0 = _b + bb0*_str + u8; \
  const __half* _p1 = _p0 + 32*_str; \
  asm volatile("global_load_dwordx4 %0, %1, off sc0 sc1" : "=v"(stg[(c)][0]) : "v"(_p0) : "memory"); \
  asm volatile("global_load_dwordx4 %0, %1, off sc0 sc1" : "=v"(stg[(c)][1]) : "v"(_p1) : "memory"); \
} while (0)

#define STORE(c) do { \
  *reinterpret_cast<u32x4*>(s.ring[(c)&3] + lds0) = stg[(c)][0]; \
  *reinterpret_cast<u32x4*>(s.ring[(c)&3] + lds1) = stg[(c)][1]; \
} while (0)

#define COMPUTE(c) do { \
  const char* _rb = s.ring[(c)&3] + rowb*128; \
  f16x8 _b0 = *reinterpret_cast<const f16x8*>(_rb + off0); \
  f16x8 _b1 = *reinterpret_cast<const f16x8*>(_rb + off1); \
  acc = __builtin_amdgcn_mfma_f32_16x16x32_f16(af[2*(c)],   _b0, acc, 0, 0, 0); \
  acc = __builtin_amdgcn_mfma_f32_16x16x32_f16(af[2*(c)+1], _b1, acc, 0, 0, 0); \
} while (0)

__global__ __launch_bounds__(NTHR, 1) void lstm2_mfma(
    const float* __restrict__ Wih0, const float* __restrict__ Whh0,
    const float* __restrict__ bih0, const float* __restrict__ bhh0,
    const float* __restrict__ Wih1, const float* __restrict__ Whh1,
    const float* __restrict__ bih1, const float* __restrict__ bhh1,
    const float* __restrict__ fcw,  const float* __restrict__ fcb,
    float* __restrict__ out, float* __restrict__ ws)
{
  extern __shared__ char smem_raw[];
  Smem& s = *reinterpret_cast<Smem*>(smem_raw);
  const int tid  = threadIdx.x;
  const int wg   = blockIdx.x;
  const int lane = tid & 63;
  const int wv   = tid >> 6;

  __half* h0s = reinterpret_cast<__half*>(ws);     // 2 x [64][512] fp16
  __half* h1s = h0s + 2*BB*HH;                     // 2 x [64][512] fp16
  unsigned* bar = reinterpret_cast<unsigned*>(reinterpret_cast<char*>(ws) + 4*BB*HH*2);
  const __half* xh = reinterpret_cast<const __half*>(reinterpret_cast<char*>(ws) + 524288);

  const int col0 = 2*wg;          // this WG owns h-columns col0, col0+1 of both layers
  const int grp  = wg >> 5;

  // ---- A-fragments: padded 16x1152 fp16 weight matrix, held in VGPRs forever ----
  // rows 0-7 = L0 (gate*2+ci), rows 8-15 = L1. K: [x 0-127 | h0 128-639 | h1 640-1151]
  f16x8 af[36];
  {
    const int r    = lane & 15;
    const int g8   = lane >> 4;           // kgroup: holds k = 32m + 8*g8 .. +7
    const int lr   = r & 7;
    const int grow = (lr >> 1)*HH + col0 + (lr & 1);
#pragma unroll
    for (int m = 0; m < 36; ++m) {
      const int k0 = 32*m + 8*g8;
      const float* src = nullptr;
      if (r < 8) {
        if (k0 < 128)              src = Wih0 + grow*DIN + k0;
        else if (k0 < 640)         src = Whh0 + grow*HH + (k0 - 128);
      } else {
        if (k0 >= 128 && k0 < 640) src = Wih1 + grow*HH + (k0 - 128);
        else if (k0 >= 640)        src = Whh1 + grow*HH + (k0 - 640);
      }
      f16x8 fr;
      if (src) {
        float4 a = *reinterpret_cast<const float4*>(src);
        float4 b = *reinterpret_cast<const float4*>(src + 4);
        fr[0]=(_Float16)a.x; fr[1]=(_Float16)a.y; fr[2]=(_Float16)a.z; fr[3]=(_Float16)a.w;
        fr[4]=(_Float16)b.x; fr[5]=(_Float16)b.y; fr[6]=(_Float16)b.z; fr[7]=(_Float16)b.w;
      } else {
#pragma unroll
        for (int j = 0; j < 8; ++j) fr[j] = (_Float16)0.f;
      }
      af[m] = fr;
    }
  }

  if (tid < 8) {
    int row = (tid >> 1)*HH + col0 + (tid & 1);
    s.bias0[tid] = bih0[row] + bhh0[row];
    s.bias1[tid] = bih1[row] + bhh1[row];
  }
  for (int i = tid; i < 2*2*64; i += NTHR) s.cst[i] = 0.0f;
  if (tid == 0) s.bar_dead = 0;
  __syncthreads();

  // staging constants: thread covers rows bb0 and bb0+32, 16B unit u0
  const int bb0  = tid >> 3;                    // 0..31
  const int u0   = tid & 7;
  const int u8   = u0*8;
  const int lds0 = bb0*128 + ((u0 ^ (bb0 & 7))*16);   // T2 XOR swizzle
  const int lds1 = lds0 + 32*128;               // (bb0+32)&7 == bb0&7
  // compute constants: wave wv owns b-cols 16wv..16wv+15
  const int rowb = 16*wv + (lane & 15);
  const int rb7  = rowb & 7;
  const int g    = lane >> 4;
  const int off0 = ((g)     ^ rb7)*16;          // MFMA0: k 0-31 of chunk
  const int off1 = ((4 + g) ^ rb7)*16;          // MFMA1: k 32-63

  for (int st = 0; st <= TT; ++st) {
    f32x4 acc = {0.f, 0.f, 0.f, 0.f};
    const __half* h0r = h0s + (st & 1)*(BB*HH);
    const __half* h1r = h1s + (st & 1)*(BB*HH);
    const int tcur = (st < TT) ? st : TT - 1;   // st=TT: x rows unused (L1 has 0-weights there)

    u32x4 stg[18][2];   // ONLY literal indices below (rule #20)

    // prologue: issue chunks 0..9 (depth-7 latency cover), store 0..2
    ISSUE(0); ISSUE(1); ISSUE(2); ISSUE(3); ISSUE(4);
    ISSUE(5); ISSUE(6); ISSUE(7); ISSUE(8); ISSUE(9);
    WAITV(18); STORE(0);
    WAITV(16); STORE(1);
    WAITV(14); STORE(2);

    // 18 slots: sync | wait+store(i+3) | issue(i+10) | compute(i)
    __syncthreads(); WAITV(12); STORE(3);  ISSUE(10); COMPUTE(0);
    __syncthreads(); WAITV(12); STORE(4);  ISSUE(11); COMPUTE(1);
    __syncthreads(); WAITV(12); STORE(5);  ISSUE(12); COMPUTE(2);
    __syncthreads(); WAITV(12); STORE(6);  ISSUE(13); COMPUTE(3);
    __syncthreads(); WAITV(12); STORE(7);  ISSUE(14); COMPUTE(4);
    __syncthreads(); WAITV(12); STORE(8);  ISSUE(15); COMPUTE(5);
    __syncthreads(); WAITV(12); STORE(9);  ISSUE(16); COMPUTE(6);
    __syncthreads(); WAITV(12); STORE(10); ISSUE(17); COMPUTE(7);
    __syncthreads(); WAITV(12); STORE(11); COMPUTE(8);
    __syncthreads(); WAITV(10); STORE(12); COMPUTE(9);
    __syncthreads(); WAITV(8);  STORE(13); COMPUTE(10);
    __syncthreads(); WAITV(6);  STORE(14); COMPUTE(11);
    __syncthreads(); WAITV(4);  STORE(15); COMPUTE(12);
    __syncthreads(); WAITV(2);  STORE(16); COMPUTE(13);
    __syncthreads(); WAITV(0);  STORE(17); COMPUTE(14);
    __syncthreads(); COMPUTE(15);
    __syncthreads(); COMPUTE(16);
    __syncthreads(); COMPUTE(17);

    // D-frag -> gates LDS: lane holds rows (lane>>4)*4+j, col rowb
    {
      const int rbase = (lane >> 4)*4;
#pragma unroll
      for (int j = 0; j < 4; ++j) s.gates[(rbase + j)*64 + rowb] = acc[j];
    }
    __syncthreads();

    // gates + state update (wave0: layer0, wave1: layer1); h -> MALL fp16
    {
      const int sel = tid >> 6;
      const int ub  = tid & 63;
      if (sel < 2) {
        const int layer = sel;
        const bool act  = (layer == 0) ? (st < TT) : (st >= 1);
        if (act) {
          const int gb = layer*8;
          const float* bsrc = layer ? s.bias1 : s.bias0;
          float hv[2];
#pragma unroll
          for (int ci = 0; ci < 2; ++ci) {
            float gi = sigm (s.gates[(gb + 0 + ci)*64 + ub] + bsrc[0 + ci]);
            float gf = sigm (s.gates[(gb + 2 + ci)*64 + ub] + bsrc[2 + ci]);
            float gg = tanhf(s.gates[(gb + 4 + ci)*64 + ub] + bsrc[4 + ci]);
            float go = sigm (s.gates[(gb + 6 + ci)*64 + ub] + bsrc[6 + ci]);
            float cprev = s.cst[(layer*2 + ci)*64 + ub];
            float cnew  = gf*cprev + gi*gg;
            s.cst[(layer*2 + ci)*64 + ub] = cnew;
            hv[ci] = go * tanhf(cnew);
          }
          __half2 hp = __floats2half2_rn(hv[0], hv[1]);
          unsigned pu = __builtin_bit_cast(unsigned, hp);
          unsigned* dst = reinterpret_cast<unsigned*>(
              (layer == 0 ? h0s : h1s) + ((st + 1) & 1)*(BB*HH));
          __hip_atomic_store(dst + ub*(HH/2) + wg, pu,
                             __ATOMIC_RELAXED, __HIP_MEMORY_SCOPE_AGENT);
        }
      }
    }
    grid_barrier(bar, grp, (unsigned)(st + 1), &s.bar_dead);
  }

  // ---- FC on last h1 (parity-1 buffer). Plain loads safe: h lines were never
  // cached (all sc-traffic) and prep_flush invalidates stale lines per call.
  {
    const __half* h1f = h1s + (BB*HH);
    int gt   = wg*NTHR + tid;
    int oidx = gt >> 3, kp = gt & 7;
    int ob   = oidx >> 7, on = oidx & 127;
    const __half* hrow = h1f + ob*HH + kp*64;
    const float*  wrow = fcw + on*HH + kp*64;
    float p = 0.f;
#pragma unroll
    for (int k = 0; k < 64; ++k) p += __half2float(hrow[k]) * wrow[k];
    p += __shfl_xor(p, 1);
    p += __shfl_xor(p, 2);
    p += __shfl_xor(p, 4);
    if (kp == 0) out[oidx] = p + fcb[on];
  }
}

__global__ void sentinel_fail(float* out, float v) { out[threadIdx.x] = v; }

extern "C" void kernel_launch(void* const* d_in, const int* in_sizes, int n_in,
                              void* d_out, int out_size, void* d_ws, size_t ws_size,
                              hipStream_t stream) {
  const float* x    = (const float*)d_in[0];
  const float* Wih0 = (const float*)d_in[1];
  const float* Whh0 = (const float*)d_in[2];
  const float* bih0 = (const float*)d_in[3];
  const float* bhh0 = (const float*)d_in[4];
  const float* Wih1 = (const float*)d_in[5];
  const float* Whh1 = (const float*)d_in[6];
  const float* bih1 = (const float*)d_in[7];
  const float* bhh1 = (const float*)d_in[8];
  const float* fcw  = (const float*)d_in[9];
  const float* fcb  = (const float*)d_in[10];
  float* out = (float*)d_out;
  float* ws  = (float*)d_ws;
  (void)in_sizes; (void)n_in; (void)out_size;

  const size_t need = 524288 + (size_t)BB*TT*DIN*2;
  if (ws_size < need) {
    sentinel_fail<<<1, 128, 0, stream>>>(out, 2.0e6f);
    return;
  }

  const int smem_bytes = 108*1024;   // > sizeof(Smem); forces 1 WG/CU
  hipFuncSetAttribute(reinterpret_cast<const void*>(&lstm2_mfma),
                      hipFuncAttributeMaxDynamicSharedMemorySize, smem_bytes);
  hipFuncSetAttribute(reinterpret_cast<const void*>(&prep_flush),
                      hipFuncAttributeMaxDynamicSharedMemorySize, smem_bytes);

  (void)hipGetLastError();
  prep_flush<<<dim3(NWG), dim3(64), smem_bytes, stream>>>();
  xcvt<<<dim3(2048), dim3(NTHR), 0, stream>>>(
      x, reinterpret_cast<unsigned long long*>(reinterpret_cast<char*>(d_ws) + 524288));
  prep_zero<<<dim3(NWG), dim3(NTHR), 0, stream>>>((unsigned*)d_ws);
  lstm2_mfma<<<dim3(NWG), dim3(NTHR), smem_bytes, stream>>>(
      Wih0, Whh0, bih0, bhh0, Wih1, Whh1, bih1, bhh1, fcw, fcb, out, ws);
  hipError_t e = hipGetLastError();
  if (e != hipSuccess) {
    sentinel_fail<<<1, 128, 0, stream>>>(out, 1.0e6f);
  }
}

// Round 7
// 8422.755 us; speedup vs baseline: 24.3496x; 1.4050x over previous
//
#include <hip/hip_runtime.h>
#include <hip/hip_fp16.h>
#include <math.h>

#define BB    64
#define TT    2048
#define DIN   128
#define HH    512
#define NWG   256
#define NTHR  256
#define NGRP  8      // batch groups (8 rows each), 32 WGs per group
#define NUNITS 1152  // staged 16B units: x 128 + h0 512 + h1 512

typedef __attribute__((ext_vector_type(4))) unsigned int u32x4;
typedef __attribute__((ext_vector_type(8))) _Float16    f16x8;
typedef __attribute__((ext_vector_type(4))) float       f32x4;

__device__ __forceinline__ float sigm(float v) { return 1.0f / (1.0f + expf(-v)); }

// Group-local (32-WG) monotonic barrier through MALL (agent-scope atomics).
__device__ __forceinline__ void group_barrier(unsigned* cnt, unsigned target, int* dead) {
  __syncthreads();
  if (threadIdx.x == 0 && *dead == 0) {
    asm volatile("s_waitcnt vmcnt(0)" ::: "memory");  // h-stores (wave 0) MALL-ack'd
    __hip_atomic_fetch_add(cnt, 1u, __ATOMIC_RELAXED, __HIP_MEMORY_SCOPE_AGENT);
    long spins = 0;
    while (__hip_atomic_load(cnt, __ATOMIC_RELAXED, __HIP_MEMORY_SCOPE_AGENT) < target) {
      __builtin_amdgcn_s_sleep(1);
      if (++spins > (1L << 22)) { *dead = 1; break; }   // no-hang valve
    }
    asm volatile("" ::: "memory");
  }
  __syncthreads();
}

// Flush every XCD's L2 (1 WG/CU via LDS capacity): stale dirty d_ws lines
// (harness poison, last replay's h) -> MALL, then invalidate.
__global__ __launch_bounds__(64, 1) void prep_flush() {
  extern __shared__ char dummy[];
  if (threadIdx.x == 0) { __threadfence(); dummy[0] = 0; }
  __syncthreads();
}

// Zero h-state + barrier words directly at MALL.
__global__ void prep_zero(unsigned* w) {
  const int total = (4*BB*HH*2 + 2048) / 4;
  for (int i = blockIdx.x*blockDim.x + threadIdx.x; i < total; i += gridDim.x*blockDim.x)
    __hip_atomic_store(w + i, 0u, __ATOMIC_RELAXED, __HIP_MEMORY_SCOPE_AGENT);
}

// x -> fp16 into ws (MALL-direct stores; readers bypass L2).
__global__ void xcvt(const float* __restrict__ x, unsigned long long* __restrict__ xh) {
  const int N4 = BB*TT*DIN/4;
  const float4* x4 = reinterpret_cast<const float4*>(x);
  for (int i = blockIdx.x*blockDim.x + threadIdx.x; i < N4; i += gridDim.x*blockDim.x) {
    float4 v = x4[i];
    __half2 a = __floats2half2_rn(v.x, v.y);
    __half2 b = __floats2half2_rn(v.z, v.w);
    unsigned long long u = ((unsigned long long)__builtin_bit_cast(unsigned, b) << 32)
                         |  (unsigned long long)__builtin_bit_cast(unsigned, a);
    __hip_atomic_store(&xh[i], u, __ATOMIC_RELAXED, __HIP_MEMORY_SCOPE_AGENT);
  }
}

__global__ __launch_bounds__(NTHR, 1) void lstm2_bsplit(
    const float* __restrict__ Wih0, const float* __restrict__ Whh0,
    const float* __restrict__ bih0, const float* __restrict__ bhh0,
    const float* __restrict__ Wih1, const float* __restrict__ Whh1,
    const float* __restrict__ bih1, const float* __restrict__ bhh1,
    const float* __restrict__ fcw,  const float* __restrict__ fcb,
    float* __restrict__ out, float* __restrict__ ws)
{
  extern __shared__ char smbase[];
  const int tid  = threadIdx.x;
  const int wg   = blockIdx.x;
  const int lane = tid & 63;
  const int wv   = tid >> 6;

  const int grp  = wg >> 5;        // batch group (8 rows)
  const int r    = wg & 31;        // rank in group -> h-cols [16r,16r+16)
  const int bg8  = grp * 8;
  const int c0   = 16*r + 4*wv;    // this wave's 4 h-cols (per layer)

  __half* h0s = reinterpret_cast<__half*>(ws);     // 2 x [64][512] fp16
  __half* h1s = h0s + 2*BB*HH;
  unsigned* gcnt = reinterpret_cast<unsigned*>(reinterpret_cast<char*>(ws) + 262144) + grp*32;
  const __half* xh = reinterpret_cast<const __half*>(reinterpret_cast<char*>(ws) + 524288);

  __half* hout = reinterpret_cast<__half*>(smbase + 18432);  // [2][8][16] halves
  int*    dead = reinterpret_cast<int*>(smbase + 18432 + 512);

  // ---- per-lane A-fragments (weights, VGPR-resident for all steps) ----
  // MFMA 16x16x32: A lane: row = lane&15, k = 32m + 8*(lane>>4) .. +7
  // tile rows r_t = gate*4 + cidx -> W row n0 = gate*512 + (c0+cidx)
  const int rt   = lane & 15;
  const int gate = rt >> 2;
  const int jc   = rt & 3;
  const int kg   = lane >> 4;
  const int n0   = gate*HH + (c0 + jc);

  f16x8 af0[20];   // L0: K=640 = [x 0-127 | h0 128-639]
#pragma unroll
  for (int m = 0; m < 20; ++m) {
    int k0 = 32*m + 8*kg;
    const float* srcp = (k0 < DIN) ? (Wih0 + (size_t)n0*DIN + k0)
                                   : (Whh0 + (size_t)n0*HH + (k0 - DIN));
    float4 a = *reinterpret_cast<const float4*>(srcp);
    float4 b = *reinterpret_cast<const float4*>(srcp + 4);
    f16x8 fr;
    fr[0]=(_Float16)a.x; fr[1]=(_Float16)a.y; fr[2]=(_Float16)a.z; fr[3]=(_Float16)a.w;
    fr[4]=(_Float16)b.x; fr[5]=(_Float16)b.y; fr[6]=(_Float16)b.z; fr[7]=(_Float16)b.w;
    af0[m] = fr;
  }
  f16x8 af1[32];   // L1: K=1024 = [h0 0-511 (W_ih1) | h1 512-1023 (W_hh1)]
#pragma unroll
  for (int m = 0; m < 32; ++m) {
    int k0 = 32*m + 8*kg;
    const float* srcp = (k0 < HH) ? (Wih1 + (size_t)n0*HH + k0)
                                  : (Whh1 + (size_t)n0*HH + (k0 - HH));
    float4 a = *reinterpret_cast<const float4*>(srcp);
    float4 b = *reinterpret_cast<const float4*>(srcp + 4);
    f16x8 fr;
    fr[0]=(_Float16)a.x; fr[1]=(_Float16)a.y; fr[2]=(_Float16)a.z; fr[3]=(_Float16)a.w;
    fr[4]=(_Float16)b.x; fr[5]=(_Float16)b.y; fr[6]=(_Float16)b.z; fr[7]=(_Float16)b.w;
    af1[m] = fr;
  }

  // ---- per-lane biases for this lane's column c0+rg (rg = lane>>4) ----
  const int rg  = lane >> 4;
  const int b15 = lane & 15;
  const int cmy = c0 + rg;
  float bv0[4], bv1[4];
#pragma unroll
  for (int g = 0; g < 4; ++g) {
    bv0[g] = bih0[g*HH + cmy] + bhh0[g*HH + cmy];
    bv1[g] = bih1[g*HH + cmy] + bhh1[g*HH + cmy];
  }

  float cst0 = 0.f, cst1 = 0.f;   // c-state for (col cmy, batch b15) in regs
  if (tid == 0) *dead = 0;
  __syncthreads();

  const int beff = (b15 < 8) ? b15 : 7;   // B-frag batch clamp (cols 8-15 unused)

  // Super-step st: L0 computes t=st (st<TT); L1 computes t=st-1 (st>=1).
  for (int st = 0; st <= TT; ++st) {
    const int tcur = (st < TT) ? st : (TT - 1);
    const __half* h0r = h0s + (st & 1)*(BB*HH);
    const __half* h1r = h1s + (st & 1)*(BB*HH);

    // ---- stage x-slice + group h0 + group h1 into LDS (18 KB, XOR-swizzled) ----
    u32x4 stgL[5];
    int   physv[5];
#pragma unroll
    for (int ii = 0; ii < 5; ++ii) {
      int idx = tid + NTHR*ii;
      physv[ii] = -1;
      if (idx < NUNITS) {
        const __half* src; int phys;
        if (idx < 128)      { int b = idx>>4, u = idx&15;
          src = xh + (size_t)(bg8+b)*TT*DIN + (size_t)tcur*DIN + u*8;
          phys = b*16 + (u ^ b); }
        else if (idx < 640) { int i2 = idx-128, b = i2>>6, u = i2&63;
          src = h0r + (size_t)(bg8+b)*HH + u*8;
          phys = 128 + b*64 + (u ^ b); }
        else                { int i2 = idx-640, b = i2>>6, u = i2&63;
          src = h1r + (size_t)(bg8+b)*HH + u*8;
          phys = 640 + b*64 + (u ^ b); }
        physv[ii] = phys;
        asm volatile("global_load_dwordx4 %0, %1, off sc0 sc1"
                     : "=v"(stgL[ii]) : "v"(src) : "memory");
      }
    }
    asm volatile("s_waitcnt vmcnt(0)" ::: "memory");
    __builtin_amdgcn_sched_barrier(0);
#pragma unroll
    for (int ii = 0; ii < 5; ++ii)
      if (physv[ii] >= 0)
        *reinterpret_cast<u32x4*>(smbase + physv[ii]*16) = stgL[ii];
    __syncthreads();

    // ---- MFMA: L0 (20) + L1 (32), 2-way acc split per layer ----
    f32x4 a0a = {0.f,0.f,0.f,0.f}, a0b = a0a, a1a = a0a, a1b = a0a;
#pragma unroll
    for (int m = 0; m < 20; ++m) {
      int phys = (m < 4) ? (beff*16 + ((4*m + kg) ^ beff))
                         : (128 + beff*64 + ((4*(m-4) + kg) ^ beff));
      f16x8 bf = *reinterpret_cast<const f16x8*>(smbase + phys*16);
      if (m & 1) a0b = __builtin_amdgcn_mfma_f32_16x16x32_f16(af0[m], bf, a0b, 0, 0, 0);
      else       a0a = __builtin_amdgcn_mfma_f32_16x16x32_f16(af0[m], bf, a0a, 0, 0, 0);
    }
#pragma unroll
    for (int m = 0; m < 32; ++m) {
      int phys = (m < 16) ? (128 + beff*64 + ((4*m + kg) ^ beff))
                          : (640 + beff*64 + ((4*(m-16) + kg) ^ beff));
      f16x8 bf = *reinterpret_cast<const f16x8*>(smbase + phys*16);
      if (m & 1) a1b = __builtin_amdgcn_mfma_f32_16x16x32_f16(af1[m], bf, a1b, 0, 0, 0);
      else       a1a = __builtin_amdgcn_mfma_f32_16x16x32_f16(af1[m], bf, a1a, 0, 0, 0);
    }
    f32x4 a0 = a0a + a0b;
    f32x4 a1 = a1a + a1b;

    // ---- gate transpose via static shuffles: lane (b15, rg=G) holds gate G,
    //      col c0+t in a*[t]. For my col (j = rg): gather gates from lanes b15+16G.
    float p00=0.f,p01=0.f,p02=0.f,p03=0.f, p10=0.f,p11=0.f,p12=0.f,p13=0.f;
#pragma unroll
    for (int t = 0; t < 4; ++t) {
      float vi = __shfl(a0[t], b15);
      float vf = __shfl(a0[t], b15 + 16);
      float vg = __shfl(a0[t], b15 + 32);
      float vo = __shfl(a0[t], b15 + 48);
      if (rg == t) { p00 = vi; p01 = vf; p02 = vg; p03 = vo; }
      float wi = __shfl(a1[t], b15);
      float wf = __shfl(a1[t], b15 + 16);
      float wgg= __shfl(a1[t], b15 + 32);
      float wo = __shfl(a1[t], b15 + 48);
      if (rg == t) { p10 = wi; p11 = wf; p12 = wgg; p13 = wo; }
    }
    const int colw = 4*wv + rg;   // col index within WG's 16
    if (st < TT) {
      float gi = sigm(p00 + bv0[0]);
      float gf = sigm(p01 + bv0[1]);
      float gg = tanhf(p02 + bv0[2]);
      float go = sigm(p03 + bv0[3]);
      cst0 = gf*cst0 + gi*gg;
      float hn = go * tanhf(cst0);
      if (b15 < 8) hout[(0*8 + b15)*16 + colw] = __float2half(hn);
    }
    if (st >= 1) {
      float gi = sigm(p10 + bv1[0]);
      float gf = sigm(p11 + bv1[1]);
      float gg = tanhf(p12 + bv1[2]);
      float go = sigm(p13 + bv1[3]);
      cst1 = gf*cst1 + gi*gg;
      float hn = go * tanhf(cst1);
      if (b15 < 8) hout[(1*8 + b15)*16 + colw] = __float2half(hn);
    }
    __syncthreads();

    // ---- pack-store h (wave 0 only: 64 x 8B agent-scope stores to MALL) ----
    if (tid < 64) {
      int layer = tid >> 5, q = tid & 31, b = q >> 2, part = q & 3;
      bool do_st = (layer == 0) ? (st < TT) : (st >= 1);
      if (do_st) {
        unsigned long long v =
            *reinterpret_cast<unsigned long long*>(hout + (layer*8 + b)*16 + part*4);
        __half* base = (layer ? h1s : h0s) + ((st + 1) & 1)*(BB*HH);
        __hip_atomic_store(
            reinterpret_cast<unsigned long long*>(base + (size_t)(bg8+b)*HH + 16*r + part*4),
            v, __ATOMIC_RELAXED, __HIP_MEMORY_SCOPE_AGENT);
      }
    }
    group_barrier(gcnt, (unsigned)(32*(st + 1)), dead);
  }

  // ---- FC on final h1 (parity 1), group-local rows, rank r -> out cols 4r..4r+3 ----
  {
    const __half* h1f = h1s + (BB*HH);
    int oi = tid >> 3, kp = tid & 7;
    int b  = oi >> 2, cc = oi & 3;
    int ocol = 4*r + cc;
    const unsigned long long* h8 =
        reinterpret_cast<const unsigned long long*>(h1f + (size_t)(bg8+b)*HH) + kp*16;
    const float* wrow = fcw + (size_t)ocol*HH + kp*64;
    float p = 0.f;
#pragma unroll
    for (int kk = 0; kk < 16; ++kk) {
      unsigned long long v = __hip_atomic_load(h8 + kk, __ATOMIC_RELAXED, __HIP_MEMORY_SCOPE_AGENT);
      __half2 hlo = __builtin_bit_cast(__half2, (unsigned)(v & 0xffffffffull));
      __half2 hhi = __builtin_bit_cast(__half2, (unsigned)(v >> 32));
      float2 flo = __half22float2(hlo), fhi = __half22float2(hhi);
      float4 w = *reinterpret_cast<const float4*>(wrow + kk*4);
      p += flo.x*w.x + flo.y*w.y + fhi.x*w.z + fhi.y*w.w;
    }
    p += __shfl_xor(p, 1);
    p += __shfl_xor(p, 2);
    p += __shfl_xor(p, 4);
    if (kp == 0) out[(size_t)(bg8+b)*128 + ocol] = p + fcb[ocol];
  }
}

__global__ void sentinel_fail(float* out, float v) { out[threadIdx.x] = v; }

extern "C" void kernel_launch(void* const* d_in, const int* in_sizes, int n_in,
                              void* d_out, int out_size, void* d_ws, size_t ws_size,
                              hipStream_t stream) {
  const float* x    = (const float*)d_in[0];
  const float* Wih0 = (const float*)d_in[1];
  const float* Whh0 = (const float*)d_in[2];
  const float* bih0 = (const float*)d_in[3];
  const float* bhh0 = (const float*)d_in[4];
  const float* Wih1 = (const float*)d_in[5];
  const float* Whh1 = (const float*)d_in[6];
  const float* bih1 = (const float*)d_in[7];
  const float* bhh1 = (const float*)d_in[8];
  const float* fcw  = (const float*)d_in[9];
  const float* fcb  = (const float*)d_in[10];
  float* out = (float*)d_out;
  float* ws  = (float*)d_ws;
  (void)in_sizes; (void)n_in; (void)out_size;

  const size_t need = 524288 + (size_t)BB*TT*DIN*2;
  if (ws_size < need) {
    sentinel_fail<<<1, 128, 0, stream>>>(out, 2.0e6f);
    return;
  }

  const int smem_bytes = 108*1024;   // >> actual use; forces 1 WG/CU
  hipFuncSetAttribute(reinterpret_cast<const void*>(&lstm2_bsplit),
                      hipFuncAttributeMaxDynamicSharedMemorySize, smem_bytes);
  hipFuncSetAttribute(reinterpret_cast<const void*>(&prep_flush),
                      hipFuncAttributeMaxDynamicSharedMemorySize, smem_bytes);

  (void)hipGetLastError();
  prep_flush<<<dim3(NWG), dim3(64), smem_bytes, stream>>>();
  xcvt<<<dim3(2048), dim3(NTHR), 0, stream>>>(
      x, reinterpret_cast<unsigned long long*>(reinterpret_cast<char*>(d_ws) + 524288));
  prep_zero<<<dim3(NWG), dim3(NTHR), 0, stream>>>((unsigned*)d_ws);
  lstm2_bsplit<<<dim3(NWG), dim3(NTHR), smem_bytes, stream>>>(
      Wih0, Whh0, bih0, bhh0, Wih1, Whh1, bih1, bhh1, fcw, fcb, out, ws);
  hipError_t e = hipGetLastError();
  if (e != hipSuccess) {
    sentinel_fail<<<1, 128, 0, stream>>>(out, 1.0e6f);
  }
}

// Round 10
// 8324.117 us; speedup vs baseline: 24.6382x; 1.0118x over previous
//
#include <hip/hip_runtime.h>
#include <hip/hip_fp16.h>
#include <math.h>

#define BB    64
#define TT    2048
#define DIN   128
#define HH    512
#define NWG   256
#define NTHR  256
#define NUNITS 1152  // staged 16B units: x 128 + h0 512 + h1 512

typedef __attribute__((ext_vector_type(4))) unsigned int u32x4;
typedef __attribute__((ext_vector_type(8))) _Float16    f16x8;
typedef __attribute__((ext_vector_type(4))) float       f32x4;

__device__ __forceinline__ float sigm(float v) { return 1.0f / (1.0f + expf(-v)); }

// ---- MALL (agent-scope) primitives — proven protocol of rounds 4-7 ----------
__device__ __forceinline__ u32x4 ld16m(const void* p) {
  u32x4 v;
  asm volatile("global_load_dwordx4 %0, %1, off sc0 sc1" : "=v"(v) : "v"(p) : "memory");
  return v;
}
__device__ __forceinline__ void st8m(void* p, unsigned long long v) {
  __hip_atomic_store((unsigned long long*)p, v, __ATOMIC_RELAXED, __HIP_MEMORY_SCOPE_AGENT);
}
__device__ __forceinline__ unsigned long long ld8m(const void* p) {
  return __hip_atomic_load((const unsigned long long*)p, __ATOMIC_RELAXED, __HIP_MEMORY_SCOPE_AGENT);
}
// group barrier (32 arrivals, monotonic counter)
__device__ __forceinline__ void gbar(unsigned* cnt, unsigned target, int* dead) {
  __syncthreads();
  if (threadIdx.x == 0 && *dead == 0) {
    asm volatile("s_waitcnt vmcnt(0)" ::: "memory");   // h-stores MALL-ack'd first
    __hip_atomic_fetch_add(cnt, 1u, __ATOMIC_RELAXED, __HIP_MEMORY_SCOPE_AGENT);
    long sp = 0;
    while (__hip_atomic_load(cnt, __ATOMIC_RELAXED, __HIP_MEMORY_SCOPE_AGENT) < target) {
      __builtin_amdgcn_s_sleep(1);
      if (++sp > (1L << 22)) { *dead = 1; break; }     // no-hang valve
    }
    asm volatile("" ::: "memory");
  }
  __syncthreads();
}

// ---- prep kernels -----------------------------------------------------------
__global__ __launch_bounds__(64, 1) void prep_flush() {
  extern __shared__ char dummy[];
  if (threadIdx.x == 0) { __threadfence(); dummy[0] = 0; }
  __syncthreads();
}
__global__ void prep_zero(unsigned* w) {
  const int total = (4*BB*HH*2 + 4096) / 4;   // h region + barrier words
  for (int i = blockIdx.x*blockDim.x + threadIdx.x; i < total; i += gridDim.x*blockDim.x)
    __hip_atomic_store(w + i, 0u, __ATOMIC_RELAXED, __HIP_MEMORY_SCOPE_AGENT);
}
__global__ void xcvt(const float* __restrict__ x, unsigned long long* __restrict__ xh) {
  const int N4 = BB*TT*DIN/4;
  const float4* x4 = reinterpret_cast<const float4*>(x);
  for (int i = blockIdx.x*blockDim.x + threadIdx.x; i < N4; i += gridDim.x*blockDim.x) {
    float4 v = x4[i];
    __half2 a = __floats2half2_rn(v.x, v.y);
    __half2 b = __floats2half2_rn(v.z, v.w);
    unsigned long long u = ((unsigned long long)__builtin_bit_cast(unsigned, b) << 32)
                         |  (unsigned long long)__builtin_bit_cast(unsigned, a);
    __hip_atomic_store(&xh[i], u, __ATOMIC_RELAXED, __HIP_MEMORY_SCOPE_AGENT);
  }
}

__global__ __launch_bounds__(NTHR, 1) void lstm2_ntr(
    const float* __restrict__ Wih0, const float* __restrict__ Whh0,
    const float* __restrict__ bih0, const float* __restrict__ bhh0,
    const float* __restrict__ Wih1, const float* __restrict__ Whh1,
    const float* __restrict__ bih1, const float* __restrict__ bhh1,
    const float* __restrict__ fcw,  const float* __restrict__ fcb,
    float* __restrict__ out, float* __restrict__ ws)
{
  extern __shared__ char smbase[];
  const int tid  = threadIdx.x;
  const int wg   = blockIdx.x;
  const int lane = tid & 63;
  const int wv   = tid >> 6;

  const int grp  = wg >> 5;        // batch group (8 rows)
  const int r    = wg & 31;        // rank in group -> h-cols [16r,16r+16)
  const int bg8  = grp * 8;
  const int c0   = 16*r + 4*wv;    // wave's 4 h-cols per layer

  __half* h0s = reinterpret_cast<__half*>(ws);     // 2 x [64][512] fp16
  __half* h1s = h0s + 2*BB*HH;
  unsigned* gcnt = reinterpret_cast<unsigned*>(reinterpret_cast<char*>(ws) + 262144) + grp*32;
  const __half* xh = reinterpret_cast<const __half*>(reinterpret_cast<char*>(ws) + 524288);
  __half* hout = reinterpret_cast<__half*>(smbase + 18432);   // [2][8][16]
  int*    dead = reinterpret_cast<int*>(smbase + 18944);

  // A-fragments. Row label rt = jc*4 + gate  ->  lane (kg,b15) C-regs j are the
  // 4 gates (i,f,g,o) of col c0+kg, batch b15. NO transpose needed after MFMA.
  const int rt   = lane & 15;
  const int gate = rt & 3;
  const int jc   = rt >> 2;
  const int kg   = lane >> 4;
  const int b15  = lane & 15;
  const int n0   = gate*HH + (c0 + jc);

  f16x8 af0[20];   // L0: K=640 = [x 0-127 | h0 128-639]
#pragma unroll
  for (int m = 0; m < 20; ++m) {
    int k0 = 32*m + 8*kg;
    const float* srcp = (k0 < DIN) ? (Wih0 + (size_t)n0*DIN + k0)
                                   : (Whh0 + (size_t)n0*HH + (k0 - DIN));
    float4 a = *reinterpret_cast<const float4*>(srcp);
    float4 b = *reinterpret_cast<const float4*>(srcp + 4);
    f16x8 fr;
    fr[0]=(_Float16)a.x; fr[1]=(_Float16)a.y; fr[2]=(_Float16)a.z; fr[3]=(_Float16)a.w;
    fr[4]=(_Float16)b.x; fr[5]=(_Float16)b.y; fr[6]=(_Float16)b.z; fr[7]=(_Float16)b.w;
    af0[m] = fr;
  }
  f16x8 af1[32];   // L1: K=1024 = [h0 (W_ih1) | h1 (W_hh1)]
#pragma unroll
  for (int m = 0; m < 32; ++m) {
    int k0 = 32*m + 8*kg;
    const float* srcp = (k0 < HH) ? (Wih1 + (size_t)n0*HH + k0)
                                  : (Whh1 + (size_t)n0*HH + (k0 - HH));
    float4 a = *reinterpret_cast<const float4*>(srcp);
    float4 b = *reinterpret_cast<const float4*>(srcp + 4);
    f16x8 fr;
    fr[0]=(_Float16)a.x; fr[1]=(_Float16)a.y; fr[2]=(_Float16)a.z; fr[3]=(_Float16)a.w;
    fr[4]=(_Float16)b.x; fr[5]=(_Float16)b.y; fr[6]=(_Float16)b.z; fr[7]=(_Float16)b.w;
    af1[m] = fr;
  }

  const int cmy = c0 + kg;            // this lane's h-column
  float bv0[4], bv1[4];
#pragma unroll
  for (int g = 0; g < 4; ++g) {
    bv0[g] = bih0[g*HH + cmy] + bhh0[g*HH + cmy];
    bv1[g] = bih1[g*HH + cmy] + bhh1[g*HH + cmy];
  }

  float cst0 = 0.f, cst1 = 0.f;
  const int beff = (b15 < 8) ? b15 : 7;
  if (tid == 0) *dead = 0;
  __syncthreads();

  for (int st = 0; st <= TT; ++st) {
    const int tcur = (st < TT) ? st : (TT - 1);
    const __half* h0r = h0s + (st & 1)*(BB*HH);
    const __half* h1r = h1s + (st & 1)*(BB*HH);

    // ---- stage x-slice + group h0 + h1 into LDS (18 KB, XOR-swizzled) ----
    u32x4 stgL[5];
    int   physv[5];
#pragma unroll
    for (int ii = 0; ii < 5; ++ii) {
      int idx = tid + NTHR*ii;
      physv[ii] = -1;
      if (idx < NUNITS) {
        const __half* src; int phys;
        if (idx < 128)      { int b = idx>>4, u = idx&15;
          src = xh + (size_t)(bg8+b)*TT*DIN + (size_t)tcur*DIN + u*8;
          phys = b*16 + (u ^ b); }
        else if (idx < 640) { int i2 = idx-128, b = i2>>6, u = i2&63;
          src = h0r + (size_t)(bg8+b)*HH + u*8;
          phys = 128 + b*64 + (u ^ b); }
        else                { int i2 = idx-640, b = i2>>6, u = i2&63;
          src = h1r + (size_t)(bg8+b)*HH + u*8;
          phys = 640 + b*64 + (u ^ b); }
        physv[ii] = phys;
        stgL[ii] = ld16m(src);
      }
    }
    asm volatile("s_waitcnt vmcnt(0)" ::: "memory");
    __builtin_amdgcn_sched_barrier(0);
#pragma unroll
    for (int ii = 0; ii < 5; ++ii)
      if (physv[ii] >= 0)
        *reinterpret_cast<u32x4*>(smbase + physv[ii]*16) = stgL[ii];
    __syncthreads();

    // ---- MFMA: L0 (20) + L1 (32), 2-way acc split ----
    f32x4 a0a = {0.f,0.f,0.f,0.f}, a0b = a0a, a1a = a0a, a1b = a0a;
#pragma unroll
    for (int m = 0; m < 20; ++m) {
      int phys = (m < 4) ? (beff*16 + ((4*m + kg) ^ beff))
                         : (128 + beff*64 + ((4*(m-4) + kg) ^ beff));
      f16x8 bf = *reinterpret_cast<const f16x8*>(smbase + phys*16);
      if (m & 1) a0b = __builtin_amdgcn_mfma_f32_16x16x32_f16(af0[m], bf, a0b, 0, 0, 0);
      else       a0a = __builtin_amdgcn_mfma_f32_16x16x32_f16(af0[m], bf, a0a, 0, 0, 0);
    }
#pragma unroll
    for (int m = 0; m < 32; ++m) {
      int phys = (m < 16) ? (128 + beff*64 + ((4*m + kg) ^ beff))
                          : (640 + beff*64 + ((4*(m-16) + kg) ^ beff));
      f16x8 bf = *reinterpret_cast<const f16x8*>(smbase + phys*16);
      if (m & 1) a1b = __builtin_amdgcn_mfma_f32_16x16x32_f16(af1[m], bf, a1b, 0, 0, 0);
      else       a1a = __builtin_amdgcn_mfma_f32_16x16x32_f16(af1[m], bf, a1a, 0, 0, 0);
    }
    f32x4 a0 = a0a + a0b;
    f32x4 a1 = a1a + a1b;

    // ---- gates directly from acc (a[j] = gate j of (col cmy, batch b15)) ----
    if (st < TT) {
      float gi = sigm (a0[0] + bv0[0]);
      float gf = sigm (a0[1] + bv0[1]);
      float gg = tanhf(a0[2] + bv0[2]);
      float go = sigm (a0[3] + bv0[3]);
      cst0 = gf*cst0 + gi*gg;
      float hn = go * tanhf(cst0);
      if (b15 < 8) hout[(0*8 + b15)*16 + 4*wv + kg] = __float2half(hn);
    }
    if (st >= 1) {
      float gi = sigm (a1[0] + bv1[0]);
      float gf = sigm (a1[1] + bv1[1]);
      float gg = tanhf(a1[2] + bv1[2]);
      float go = sigm (a1[3] + bv1[3]);
      cst1 = gf*cst1 + gi*gg;
      float hn = go * tanhf(cst1);
      if (b15 < 8) hout[(1*8 + b15)*16 + 4*wv + kg] = __float2half(hn);
    }
    __syncthreads();

    // ---- pack-store h (wave 0: 64 x 8B agent-scope stores to MALL) ----
    if (tid < 64) {
      int layer = tid >> 5, q = tid & 31, b = q >> 2, part = q & 3;
      bool do_st = (layer == 0) ? (st < TT) : (st >= 1);
      if (do_st) {
        unsigned long long v =
            *reinterpret_cast<unsigned long long*>(hout + (layer*8 + b)*16 + part*4);
        __half* base = (layer ? h1s : h0s) + ((st + 1) & 1)*(BB*HH);
        st8m(base + (size_t)(bg8+b)*HH + 16*r + part*4, v);
      }
    }
    gbar(gcnt, 32u*(unsigned)(st + 1), dead);
  }

  // ---- FC on final h1 (parity 1) ----
  {
    const __half* h1f = h1s + (BB*HH);
    int oi = tid >> 3, kp = tid & 7;
    int b  = oi >> 2, cc = oi & 3;
    int ocol = 4*r + cc;
    const unsigned long long* h8 =
        reinterpret_cast<const unsigned long long*>(h1f + (size_t)(bg8+b)*HH) + kp*16;
    const float* wrow = fcw + (size_t)ocol*HH + kp*64;
    float p = 0.f;
#pragma unroll
    for (int kk = 0; kk < 16; ++kk) {
      unsigned long long v = ld8m(h8 + kk);
      __half2 hlo = __builtin_bit_cast(__half2, (unsigned)(v & 0xffffffffull));
      __half2 hhi = __builtin_bit_cast(__half2, (unsigned)(v >> 32));
      float2 flo = __half22float2(hlo), fhi = __half22float2(hhi);
      float4 w = *reinterpret_cast<const float4*>(wrow + kk*4);
      p += flo.x*w.x + flo.y*w.y + fhi.x*w.z + fhi.y*w.w;
    }
    p += __shfl_xor(p, 1);
    p += __shfl_xor(p, 2);
    p += __shfl_xor(p, 4);
    if (kp == 0) out[(size_t)(bg8+b)*128 + ocol] = p + fcb[ocol];
  }
}

__global__ void sentinel_fail(float* out, float v) { out[threadIdx.x] = v; }

extern "C" void kernel_launch(void* const* d_in, const int* in_sizes, int n_in,
                              void* d_out, int out_size, void* d_ws, size_t ws_size,
                              hipStream_t stream) {
  const float* x    = (const float*)d_in[0];
  const float* Wih0 = (const float*)d_in[1];
  const float* Whh0 = (const float*)d_in[2];
  const float* bih0 = (const float*)d_in[3];
  const float* bhh0 = (const float*)d_in[4];
  const float* Wih1 = (const float*)d_in[5];
  const float* Whh1 = (const float*)d_in[6];
  const float* bih1 = (const float*)d_in[7];
  const float* bhh1 = (const float*)d_in[8];
  const float* fcw  = (const float*)d_in[9];
  const float* fcb  = (const float*)d_in[10];
  float* out = (float*)d_out;
  float* ws  = (float*)d_ws;
  (void)in_sizes; (void)n_in; (void)out_size;

  const size_t need = 524288 + (size_t)BB*TT*DIN*2;
  if (ws_size < need) {
    sentinel_fail<<<1, 128, 0, stream>>>(out, 2.0e6f);
    return;
  }

  const int smem_bytes = 108*1024;   // forces 1 WG/CU
  hipFuncSetAttribute(reinterpret_cast<const void*>(&lstm2_ntr),
                      hipFuncAttributeMaxDynamicSharedMemorySize, smem_bytes);
  hipFuncSetAttribute(reinterpret_cast<const void*>(&prep_flush),
                      hipFuncAttributeMaxDynamicSharedMemorySize, smem_bytes);

  (void)hipGetLastError();
  prep_flush<<<dim3(NWG), dim3(64), smem_bytes, stream>>>();
  xcvt<<<dim3(2048), dim3(NTHR), 0, stream>>>(
      x, reinterpret_cast<unsigned long long*>(reinterpret_cast<char*>(d_ws) + 524288));
  prep_zero<<<dim3(NWG), dim3(NTHR), 0, stream>>>((unsigned*)d_ws);
  lstm2_ntr<<<dim3(NWG), dim3(NTHR), smem_bytes, stream>>>(
      Wih0, Whh0, bih0, bhh0, Wih1, Whh1, bih1, bhh1, fcw, fcb, out, ws);
  hipError_t e = hipGetLastError();
  if (e != hipSuccess) {
    sentinel_fail<<<1, 128, 0, stream>>>(out, 1.0e6f);
  }
}